// Round 4
// baseline (20.930 us; speedup 1.0000x reference)
//
#include <hip/hip_runtime.h>

#define NQ 16
#define DIM 65536          // 2^16
#define BPB 8              // blocks per batch row
#define CHUNK (DIM / BPB)  // 8192 floats per block
#define TAB_BYTES (256 * 512 * 4)  // 256 batches x (256 low + 256 high) floats

typedef float f32x4 __attribute__((ext_vector_type(4)));

// out[b, i] = prod_q p_q[bit_q(i)]  (product state -> separable probabilities)
// Factor: out[i] = low8[i & 255] * high8[i >> 8]

// ---- k1: build per-batch product tables into ws[b*512 + {0..255 lo, 256..511 hi}]
__global__ __launch_bounds__(64) void qtab_kernel(
    const float* __restrict__ emb,   // [B, 768]
    const float* __restrict__ rot,   // [16, 3]
    float* __restrict__ ws)
{
    __shared__ float p0s[NQ], p1s[NQ];
    const int b = blockIdx.x;
    const int t = threadIdx.x;

    if (t < NQ) {
        const float rx = emb[b * 768 + t * 3 + 0] + rot[t * 3 + 0];
        const float ry = emb[b * 768 + t * 3 + 1] + rot[t * 3 + 1];
        float sx, cx, sy, cy;
        sincosf(rx * 0.5f, &sx, &cx);
        sincosf(ry * 0.5f, &sy, &cy);
        const float cx2 = cx * cx, sx2 = sx * sx;
        const float cy2 = cy * cy, sy2 = sy * sy;
        p0s[t] = cx2 * cy2 + sx2 * sy2;   // Rz is pure phase -> only rx, ry matter
        p1s[t] = cx2 * sy2 + sx2 * cy2;
    }
    __syncthreads();

    f32x4 lo4, hi4;
#pragma unroll
    for (int e = 0; e < 4; ++e) {
        const int idx = t * 4 + e;
        float lo = 1.0f, hi = 1.0f;
#pragma unroll
        for (int q = 0; q < 8; ++q) {
            lo *= ((idx >> q) & 1) ? p1s[q]     : p0s[q];
            hi *= ((idx >> q) & 1) ? p1s[q + 8] : p0s[q + 8];
        }
        lo4[e] = lo;
        hi4[e] = hi;
    }
    *(f32x4*)&ws[b * 512 + t * 4]       = lo4;
    *(f32x4*)&ws[b * 512 + 256 + t * 4] = hi4;
}

// ---- k2: barrier-free, LDS-free streaming writer
__global__ __launch_bounds__(256) void qwrite_kernel(
    const float* __restrict__ ws,
    float* __restrict__ out)
{
    const int b = blockIdx.x / BPB;
    const int j = blockIdx.x % BPB;
    const int t = threadIdx.x;
    const float* tab = ws + b * 512;

    const f32x4 lv = *(const f32x4*)&tab[(4 * t) & 255];

    const int hb = j * (CHUNK >> 8) + (t >> 6);   // wave-uniform
    float h[CHUNK / 1024];
#pragma unroll
    for (int k = 0; k < CHUNK / 1024; ++k)
        h[k] = tab[256 + hb + 4 * k];

    f32x4* outrow = (f32x4*)(out + (size_t)b * DIM + (size_t)j * CHUNK);
#pragma unroll
    for (int k = 0; k < CHUNK / 1024; ++k)
        __builtin_nontemporal_store(lv * h[k], &outrow[k * 256 + t]);
}

// ---- fallback: single fused kernel (round-3 version) if ws is too small
__global__ __launch_bounds__(256) void qprob_kernel(
    const float* __restrict__ emb,
    const float* __restrict__ rot,
    float* __restrict__ out)
{
    __shared__ float p0s[NQ], p1s[NQ];
    __shared__ float low8[256];
    __shared__ float high8[256];

    const int b = blockIdx.x / BPB;
    const int j = blockIdx.x % BPB;
    const int t = threadIdx.x;

    if (t < NQ) {
        const float rx = emb[b * 768 + t * 3 + 0] + rot[t * 3 + 0];
        const float ry = emb[b * 768 + t * 3 + 1] + rot[t * 3 + 1];
        float sx, cx, sy, cy;
        sincosf(rx * 0.5f, &sx, &cx);
        sincosf(ry * 0.5f, &sy, &cy);
        const float cx2 = cx * cx, sx2 = sx * sx;
        const float cy2 = cy * cy, sy2 = sy * sy;
        p0s[t] = cx2 * cy2 + sx2 * sy2;
        p1s[t] = cx2 * sy2 + sx2 * cy2;
    }
    __syncthreads();

    float lo = 1.0f, hi = 1.0f;
#pragma unroll
    for (int q = 0; q < 8; ++q) {
        lo *= ((t >> q) & 1) ? p1s[q]     : p0s[q];
        hi *= ((t >> q) & 1) ? p1s[q + 8] : p0s[q + 8];
    }
    low8[t] = lo;
    high8[t] = hi;
    __syncthreads();

    const int l = (4 * t) & 255;
    const f32x4 lv = *(const f32x4*)&low8[l];

    const int hb = j * (CHUNK >> 8) + (t >> 6);
    float h[CHUNK / 1024];
#pragma unroll
    for (int k = 0; k < CHUNK / 1024; ++k)
        h[k] = high8[hb + 4 * k];

    f32x4* outrow = (f32x4*)(out + (size_t)b * DIM + (size_t)j * CHUNK);
#pragma unroll
    for (int k = 0; k < CHUNK / 1024; ++k)
        __builtin_nontemporal_store(lv * h[k], &outrow[k * 256 + t]);
}

extern "C" void kernel_launch(void* const* d_in, const int* in_sizes, int n_in,
                              void* d_out, int out_size, void* d_ws, size_t ws_size,
                              hipStream_t stream) {
    const float* emb = (const float*)d_in[0];  // [B, 768] float32
    const float* rot = (const float*)d_in[1];  // [16, 3]  float32
    float* out = (float*)d_out;                // [B, 65536] float32

    const int B = in_sizes[0] / 768;           // 256

    if (ws_size >= (size_t)TAB_BYTES) {
        float* ws = (float*)d_ws;
        qtab_kernel<<<dim3(B), dim3(64), 0, stream>>>(emb, rot, ws);
        qwrite_kernel<<<dim3(B * BPB), dim3(256), 0, stream>>>(ws, out);
    } else {
        qprob_kernel<<<dim3(B * BPB), dim3(256), 0, stream>>>(emb, rot, out);
    }
}

// Round 5
// 16.694 us; speedup vs baseline: 1.2537x; 1.2537x over previous
//
#include <hip/hip_runtime.h>

#define NQ 16
#define DIM 65536          // 2^16
#define BPB 8              // blocks per batch row
#define CHUNK (DIM / BPB)  // 8192 floats per block

typedef float f32x4 __attribute__((ext_vector_type(4)));

// out[b, i] = prod_q p_q[bit_q(i)]  (product state -> separable probabilities).
// Rz is a pure phase -> only rx, ry matter:
//   p_q[0] = cx^2 cy^2 + sx^2 sy^2,  p_q[1] = cx^2 sy^2 + sx^2 cy^2.
// Factor out[i] = low(i & 255) * high(i >> 8); both computed per-thread in
// registers from wave-shuffled per-qubit probabilities. No LDS, no barriers.
__global__ __launch_bounds__(256) void qprob_kernel(
    const float* __restrict__ emb,   // [B, 768] (only first 48 cols used)
    const float* __restrict__ rot,   // [16, 3]
    float* __restrict__ out)         // [B, 65536]
{
    const int b = blockIdx.x >> 3;   // / BPB
    const int j = blockIdx.x & (BPB - 1);
    const int t = threadIdx.x;
    const int q = t & 15;            // every lane computes qubit (lane&15)

    const float rx = emb[b * 768 + q * 3 + 0] + rot[q * 3 + 0];
    const float ry = emb[b * 768 + q * 3 + 1] + rot[q * 3 + 1];
    float sx, cx, sy, cy;
    sincosf(rx * 0.5f, &sx, &cx);
    sincosf(ry * 0.5f, &sy, &cy);
    const float cx2 = cx * cx, sx2 = sx * sx;
    const float cy2 = cy * cy, sy2 = sy * sy;
    const float p0 = cx2 * cy2 + sx2 * sy2;
    const float p1 = cx2 * sy2 + sx2 * cy2;

    // Broadcast all 16 (p0,p1) pairs across the wave (lane qq holds qubit qq).
    float P0[NQ], P1[NQ];
#pragma unroll
    for (int qq = 0; qq < NQ; ++qq) {
        P0[qq] = __shfl(p0, qq, 64);
        P1[qq] = __shfl(p1, qq, 64);
    }

    // Low factors: this thread's 4 consecutive elements idx = ((4t)&255)+e.
    const int base = (4 * t) & 255;  // bits 0-1 are zero
    float locom = 1.0f;
#pragma unroll
    for (int qq = 2; qq < 8; ++qq)
        locom *= ((base >> qq) & 1) ? P1[qq] : P0[qq];
    f32x4 lv;
    lv.x = locom * (P0[0] * P0[1]);
    lv.y = locom * (P1[0] * P0[1]);
    lv.z = locom * (P0[0] * P1[1]);
    lv.w = locom * (P1[0] * P1[1]);

    // High factors: idx_h(k) = j*32 + (t>>6) + 4k  -> qubit 8+m selects bit m.
    const int tb = t >> 6;           // bits 0-1
    float hcom = ((tb & 1) ? P1[8] : P0[8]) * ((tb & 2) ? P1[9] : P0[9]);
#pragma unroll
    for (int m = 0; m < 3; ++m)
        hcom *= ((j >> m) & 1) ? P1[13 + m] : P0[13 + m];
    float h[CHUNK / 1024];
#pragma unroll
    for (int k = 0; k < CHUNK / 1024; ++k) {     // bits 2-4 = k
        float v = hcom;
        v *= (k & 1) ? P1[10] : P0[10];
        v *= (k & 2) ? P1[11] : P0[11];
        v *= (k & 4) ? P1[12] : P0[12];
        h[k] = v;
    }

    f32x4* outrow = (f32x4*)(out + (size_t)b * DIM + (size_t)j * CHUNK);
#pragma unroll
    for (int k = 0; k < CHUNK / 1024; ++k)       // 8 independent nt-stores
        __builtin_nontemporal_store(lv * h[k], &outrow[k * 256 + t]);
}

extern "C" void kernel_launch(void* const* d_in, const int* in_sizes, int n_in,
                              void* d_out, int out_size, void* d_ws, size_t ws_size,
                              hipStream_t stream) {
    const float* emb = (const float*)d_in[0];  // [B, 768] float32
    const float* rot = (const float*)d_in[1];  // [16, 3]  float32
    float* out = (float*)d_out;                // [B, 65536] float32

    const int B = in_sizes[0] / 768;           // 256
    qprob_kernel<<<dim3(B * BPB), dim3(256), 0, stream>>>(emb, rot, out);
}